// Round 7
// baseline (158.444 us; speedup 1.0000x reference)
//
#include <hip/hip_runtime.h>
#include <math.h>

#define N_NODES 20000
#define N_EDGES 320000
#define EMB 256
#define CAP 64                              // slots per node; actual max in-degree ~40 (Poisson 16)
#define NGRP 8                              // channel groups == XCD count
#define GCH 32                              // channels per group
#define GEMM_BLOCKS (N_NODES / 32)          // 625
#define SCAT_BLOCKS ((N_EDGES + 255) / 256) // 1250
#define LDS_PITCH 264                       // 256 + 8 shorts: breaks bank-stride, keeps 16B align

typedef __attribute__((ext_vector_type(8))) short short8;
typedef __attribute__((ext_vector_type(4))) float floatx4;

__device__ __forceinline__ unsigned short bf16r(float x) {
    unsigned u = __float_as_uint(x);
    u += 0x7fffu + ((u >> 16) & 1u);
    return (unsigned short)(u >> 16);
}

// ---------- init: convert W_self to bf16 + zero slot counters ----------
__global__ __launch_bounds__(256) void init_kernel(
        const float* __restrict__ W, unsigned short* __restrict__ Wb,
        int* __restrict__ cnt) {
    int gid = blockIdx.x * 256 + threadIdx.x;
    if (gid < N_NODES) cnt[gid] = 0;
    if (gid < (EMB * EMB) / 8) {
        long off = (long)gid * 8;
        float4 x = *(const float4*)(W + off);
        float4 y = *(const float4*)(W + off + 4);
        uint4 o;
        o.x = (unsigned)bf16r(x.x) | ((unsigned)bf16r(x.y) << 16);
        o.y = (unsigned)bf16r(x.z) | ((unsigned)bf16r(x.w) << 16);
        o.z = (unsigned)bf16r(y.x) | ((unsigned)bf16r(y.y) << 16);
        o.w = (unsigned)bf16r(y.z) | ((unsigned)bf16r(y.w) << 16);
        *(uint4*)(Wb + off) = o;
    }
}

// ---------------------------------------------------------------------------
// GEMM tile body: S = h @ W_self^T for 32 rows.  Output layout is GROUP-MAJOR:
// packed[g][node][c] (g = ch>>5, c = ch&31) so each channel-group's gather
// slice is 2.56 MB — one XCD's L2.  C/D layout (col=lane&15, row=(lane>>4)*4+reg)
// harness-verified R2..R6; 16 consecutive cols stay within one group, so the
// epilogue still writes 64B segments.
// ---------------------------------------------------------------------------
__device__ __forceinline__ void gemm_tile(
        const float* __restrict__ h, const unsigned short* __restrict__ Wb,
        unsigned int* __restrict__ packed, unsigned short (*At)[LDS_PITCH],
        int b, int t) {
    int w = t >> 6, l = t & 63;
    int m0 = b * 32;
    int n0 = w * 64;
    int lm = l & 15, lk = (l >> 4) * 8;

    // stage A: 32 rows x 256 cols fp32 -> bf16 LDS, coalesced float4 reads
#pragma unroll
    for (int it = 0; it < 8; ++it) {
        int q = it * 256 + t;            // [0, 2048)
        int row = q >> 6;                // 64 float4 per row
        int c4 = (q & 63) * 4;
        float4 x = *(const float4*)(h + (size_t)(m0 + row) * EMB + c4);
        At[row][c4 + 0] = bf16r(x.x);
        At[row][c4 + 1] = bf16r(x.y);
        At[row][c4 + 2] = bf16r(x.z);
        At[row][c4 + 3] = bf16r(x.w);
    }
    __syncthreads();

    floatx4 acc[2][4];
#pragma unroll
    for (int mt = 0; mt < 2; ++mt)
#pragma unroll
        for (int nt = 0; nt < 4; ++nt) acc[mt][nt] = (floatx4){0.f, 0.f, 0.f, 0.f};

    const unsigned short* a0p = &At[lm][lk];
    const unsigned short* a1p = &At[16 + lm][lk];
    const unsigned short* bp = Wb + (size_t)(n0 + lm) * EMB + lk;

#pragma unroll
    for (int k0 = 0; k0 < EMB; k0 += 32) {
        short8 a0 = *(const short8*)(a0p + k0);
        short8 a1 = *(const short8*)(a1p + k0);
        short8 b0 = *(const short8*)(bp + k0);
        short8 b1 = *(const short8*)(bp + 16 * EMB + k0);
        short8 b2 = *(const short8*)(bp + 32 * EMB + k0);
        short8 b3 = *(const short8*)(bp + 48 * EMB + k0);
        acc[0][0] = __builtin_amdgcn_mfma_f32_16x16x32_bf16(a0, b0, acc[0][0], 0, 0, 0);
        acc[0][1] = __builtin_amdgcn_mfma_f32_16x16x32_bf16(a0, b1, acc[0][1], 0, 0, 0);
        acc[0][2] = __builtin_amdgcn_mfma_f32_16x16x32_bf16(a0, b2, acc[0][2], 0, 0, 0);
        acc[0][3] = __builtin_amdgcn_mfma_f32_16x16x32_bf16(a0, b3, acc[0][3], 0, 0, 0);
        acc[1][0] = __builtin_amdgcn_mfma_f32_16x16x32_bf16(a1, b0, acc[1][0], 0, 0, 0);
        acc[1][1] = __builtin_amdgcn_mfma_f32_16x16x32_bf16(a1, b1, acc[1][1], 0, 0, 0);
        acc[1][2] = __builtin_amdgcn_mfma_f32_16x16x32_bf16(a1, b2, acc[1][2], 0, 0, 0);
        acc[1][3] = __builtin_amdgcn_mfma_f32_16x16x32_bf16(a1, b3, acc[1][3], 0, 0, 0);
    }

    // direct epilogue: group-major store, bf16(h) partner from At
#pragma unroll
    for (int mt = 0; mt < 2; ++mt)
#pragma unroll
        for (int nt = 0; nt < 4; ++nt) {
            int col = n0 + nt * 16 + lm;
            int g = col >> 5, c = col & 31;
#pragma unroll
            for (int r = 0; r < 4; ++r) {
                int row = mt * 16 + (l >> 4) * 4 + r;
                unsigned u = (unsigned)bf16r(__expf(acc[mt][nt][r])) |
                             ((unsigned)At[row][col] << 16);
                packed[((size_t)g * N_NODES + (m0 + row)) * GCH + c] = u;
            }
        }
}

// ---------- merged independent work: gemm (blocks 0..624) | bucket scatter ----------
__global__ __launch_bounds__(256) void scatter_gemm_kernel(
        const float* __restrict__ h, const unsigned short* __restrict__ Wb,
        unsigned int* __restrict__ packed, const int* __restrict__ src,
        const int* __restrict__ dst, int* __restrict__ cnt,
        unsigned short* __restrict__ csr_src) {
    if (blockIdx.x < GEMM_BLOCKS) {
        __shared__ unsigned short At[32][LDS_PITCH];
        gemm_tile(h, Wb, packed, At, blockIdx.x, threadIdx.x);
    } else {
        int i = (blockIdx.x - GEMM_BLOCKS) * 256 + threadIdx.x;
        if (i < N_EDGES) {
            int d = dst[i];
            int slot = atomicAdd(&cnt[d], 1);
            slot = min(slot, CAP - 1);  // never OOB even on hypothetical overflow
            csr_src[(size_t)d * CAP + slot] = (unsigned short)src[i];
        }
    }
}

// ---------- aggregate: XCD-partitioned channel groups ----------
// Block bid handles channel-group g = bid&7 for 4 nodes; with round-robin
// block->XCD dispatch, XCD x runs ONLY group x -> its 2.56 MB packed slice is
// L2-resident and the 327 MB logical gather is served at L2 rate, not L3.
// Wave layout: lane = edge_slot(l>>3)*8 + ch_octet(l&7); 8 edges in parallel,
// 128 B per edge; butterfly-reduce across edge slots at the end.
#define PROC(p)                                                                  \
    {                                                                            \
        unsigned u;                                                              \
        float e, hv;                                                             \
        u = (p).x; e = __uint_as_float(u << 16);                                 \
        hv = __uint_as_float(u & 0xffff0000u); ss0 += e; a0 = fmaf(e, hv, a0);   \
        u = (p).y; e = __uint_as_float(u << 16);                                 \
        hv = __uint_as_float(u & 0xffff0000u); ss1 += e; a1 = fmaf(e, hv, a1);   \
        u = (p).z; e = __uint_as_float(u << 16);                                 \
        hv = __uint_as_float(u & 0xffff0000u); ss2 += e; a2 = fmaf(e, hv, a2);   \
        u = (p).w; e = __uint_as_float(u << 16);                                 \
        hv = __uint_as_float(u & 0xffff0000u); ss3 += e; a3 = fmaf(e, hv, a3);   \
    }
#define LOADC(k) uint4 q##k; { int e = (k)*8 + es; if (e < d) {                  \
        int s = (int)seg[e]; q##k = pg[(size_t)s * 8 + c8]; } }
#define PROCC(k) { int e = (k)*8 + es; if (e < d) PROC(q##k) }

__global__ __launch_bounds__(256) void aggregate_kernel(
        const float* __restrict__ h, const uint4* __restrict__ packed,
        const int* __restrict__ cnt, const unsigned short* __restrict__ csr_src,
        float* __restrict__ out) {
    int w = threadIdx.x >> 6, l = threadIdx.x & 63;
    int bid = blockIdx.x;
    int g = bid & 7;                      // == XCD under round-robin dispatch
    int node = (bid >> 3) * 4 + w;
    int d = min(cnt[node], CAP);
    int es = l >> 3;                      // edge slot 0..7
    int c8 = l & 7;                       // channel octet within group
    if (d == 0) {                         // zero in-degree: pass through h
        if (l < 8) {
            float4 v = *(const float4*)(h + (size_t)node * EMB + g * GCH + l * 4);
            *(float4*)(out + (size_t)node * EMB + g * GCH + l * 4) = v;
        }
        return;
    }
    const unsigned short* seg = csr_src + (size_t)node * CAP;
    const uint4* pg = packed + (size_t)g * N_NODES * 8;  // 8 uint4 per node-row
    float ss0 = 0.f, ss1 = 0.f, ss2 = 0.f, ss3 = 0.f;
    float a0 = 0.f, a1 = 0.f, a2 = 0.f, a3 = 0.f;
    // chunks of 8 edges; 2 issued up front (covers d<=16, ~85% of nodes)
    LOADC(0) LOADC(1) PROCC(0) PROCC(1)
    if (d > 16) { LOADC(2) LOADC(3) PROCC(2) PROCC(3) }
    if (d > 32) {
        LOADC(4) LOADC(5) LOADC(6) LOADC(7)
        PROCC(4) PROCC(5) PROCC(6) PROCC(7)
    }
    // butterfly reduce across edge slots (strides 8,16,32)
#pragma unroll
    for (int st = 8; st < 64; st <<= 1) {
        ss0 += __shfl_xor(ss0, st); ss1 += __shfl_xor(ss1, st);
        ss2 += __shfl_xor(ss2, st); ss3 += __shfl_xor(ss3, st);
        a0  += __shfl_xor(a0,  st); a1  += __shfl_xor(a1,  st);
        a2  += __shfl_xor(a2,  st); a3  += __shfl_xor(a3,  st);
    }
    if (l < 8) {
        float4 o;
        o.x = a0 / ss0; o.y = a1 / ss1; o.z = a2 / ss2; o.w = a3 / ss3;
        *(float4*)(out + (size_t)node * EMB + g * GCH + l * 4) = o;
    }
}

// ---------- launch ----------
extern "C" void kernel_launch(void* const* d_in, const int* in_sizes, int n_in,
                              void* d_out, int out_size, void* d_ws, size_t ws_size,
                              hipStream_t stream) {
    const float* h      = (const float*)d_in[0];
    // W_nb (d_in[1]), b_nb (d_in[2]), b_self (d_in[4]) are mathematically
    // irrelevant: constant per (dst, channel) inside each softmax segment,
    // cancel exactly in alpha = e / seg_sum.
    const float* W_self = (const float*)d_in[3];
    const int*   src    = (const int*)d_in[5];
    const int*   dst    = (const int*)d_in[6];
    float* out = (float*)d_out;

    char* ws = (char*)d_ws;
    unsigned int* packed = (unsigned int*)ws;   // [8][N,32] group-major (E,h) pairs
    size_t off = (size_t)N_NODES * EMB * sizeof(unsigned int);
    unsigned short* Wb = (unsigned short*)(ws + off); off += (size_t)EMB * EMB * sizeof(unsigned short);
    int* cnt = (int*)(ws + off); off += (size_t)N_NODES * sizeof(int);
    unsigned short* csr_src = (unsigned short*)(ws + off);
    off += (size_t)N_NODES * CAP * sizeof(unsigned short);

    init_kernel<<<(N_NODES + 255) / 256, 256, 0, stream>>>(W_self, Wb, cnt);
    scatter_gemm_kernel<<<GEMM_BLOCKS + SCAT_BLOCKS, 256, 0, stream>>>(
        h, Wb, packed, src, dst, cnt, csr_src);
    aggregate_kernel<<<(N_NODES / 4) * NGRP, 256, 0, stream>>>(
        h, (const uint4*)packed, cnt, csr_src, out);
}

// Round 9
// 144.548 us; speedup vs baseline: 1.0961x; 1.0961x over previous
//
#include <hip/hip_runtime.h>
#include <math.h>

#define N_NODES 20000
#define N_EDGES 320000
#define EMB 256
#define CAP 64                              // slots per node; actual max in-degree ~40 (Poisson 16)
#define NGRP 8                              // channel groups == XCD count
#define GCH 32                              // channels per group
#define GEMM_BLOCKS (N_NODES / 32)          // 625
#define SCAT_BLOCKS ((N_EDGES + 255) / 256) // 1250
#define LDS_PITCH 264                       // 256 + 8 shorts: breaks bank-stride, keeps 16B align

typedef __attribute__((ext_vector_type(8))) short short8;
typedef __attribute__((ext_vector_type(4))) float floatx4;

__device__ __forceinline__ unsigned short bf16r(float x) {
    unsigned u = __float_as_uint(x);
    u += 0x7fffu + ((u >> 16) & 1u);
    return (unsigned short)(u >> 16);
}

// ---------- init: convert W_self to bf16 + zero slot counters ----------
__global__ __launch_bounds__(256) void init_kernel(
        const float* __restrict__ W, unsigned short* __restrict__ Wb,
        int* __restrict__ cnt) {
    int gid = blockIdx.x * 256 + threadIdx.x;
    if (gid < N_NODES) cnt[gid] = 0;
    if (gid < (EMB * EMB) / 8) {
        long off = (long)gid * 8;
        float4 x = *(const float4*)(W + off);
        float4 y = *(const float4*)(W + off + 4);
        uint4 o;
        o.x = (unsigned)bf16r(x.x) | ((unsigned)bf16r(x.y) << 16);
        o.y = (unsigned)bf16r(x.z) | ((unsigned)bf16r(x.w) << 16);
        o.z = (unsigned)bf16r(y.x) | ((unsigned)bf16r(y.y) << 16);
        o.w = (unsigned)bf16r(y.z) | ((unsigned)bf16r(y.w) << 16);
        *(uint4*)(Wb + off) = o;
    }
}

// ---------------------------------------------------------------------------
// GEMM tile body: S = h @ W_self^T for 32 rows.  Output layout GROUP-MAJOR:
// packed[g][node][c] (g = ch>>5, c = ch&31): each group's gather slice is
// 2.56 MB — one XCD's L2 (FETCH 133->21 MB harness-verified R7).
// C/D layout (col=lane&15, row=(lane>>4)*4+reg) harness-verified R2..R7.
// ---------------------------------------------------------------------------
__device__ __forceinline__ void gemm_tile(
        const float* __restrict__ h, const unsigned short* __restrict__ Wb,
        unsigned int* __restrict__ packed, unsigned short (*At)[LDS_PITCH],
        int b, int t) {
    int w = t >> 6, l = t & 63;
    int m0 = b * 32;
    int n0 = w * 64;
    int lm = l & 15, lk = (l >> 4) * 8;

    // stage A: 32 rows x 256 cols fp32 -> bf16 LDS, coalesced float4 reads
#pragma unroll
    for (int it = 0; it < 8; ++it) {
        int q = it * 256 + t;            // [0, 2048)
        int row = q >> 6;                // 64 float4 per row
        int c4 = (q & 63) * 4;
        float4 x = *(const float4*)(h + (size_t)(m0 + row) * EMB + c4);
        At[row][c4 + 0] = bf16r(x.x);
        At[row][c4 + 1] = bf16r(x.y);
        At[row][c4 + 2] = bf16r(x.z);
        At[row][c4 + 3] = bf16r(x.w);
    }
    __syncthreads();

    floatx4 acc[2][4];
#pragma unroll
    for (int mt = 0; mt < 2; ++mt)
#pragma unroll
        for (int nt = 0; nt < 4; ++nt) acc[mt][nt] = (floatx4){0.f, 0.f, 0.f, 0.f};

    const unsigned short* a0p = &At[lm][lk];
    const unsigned short* a1p = &At[16 + lm][lk];
    const unsigned short* bp = Wb + (size_t)(n0 + lm) * EMB + lk;

#pragma unroll
    for (int k0 = 0; k0 < EMB; k0 += 32) {
        short8 a0 = *(const short8*)(a0p + k0);
        short8 a1 = *(const short8*)(a1p + k0);
        short8 b0 = *(const short8*)(bp + k0);
        short8 b1 = *(const short8*)(bp + 16 * EMB + k0);
        short8 b2 = *(const short8*)(bp + 32 * EMB + k0);
        short8 b3 = *(const short8*)(bp + 48 * EMB + k0);
        acc[0][0] = __builtin_amdgcn_mfma_f32_16x16x32_bf16(a0, b0, acc[0][0], 0, 0, 0);
        acc[0][1] = __builtin_amdgcn_mfma_f32_16x16x32_bf16(a0, b1, acc[0][1], 0, 0, 0);
        acc[0][2] = __builtin_amdgcn_mfma_f32_16x16x32_bf16(a0, b2, acc[0][2], 0, 0, 0);
        acc[0][3] = __builtin_amdgcn_mfma_f32_16x16x32_bf16(a0, b3, acc[0][3], 0, 0, 0);
        acc[1][0] = __builtin_amdgcn_mfma_f32_16x16x32_bf16(a1, b0, acc[1][0], 0, 0, 0);
        acc[1][1] = __builtin_amdgcn_mfma_f32_16x16x32_bf16(a1, b1, acc[1][1], 0, 0, 0);
        acc[1][2] = __builtin_amdgcn_mfma_f32_16x16x32_bf16(a1, b2, acc[1][2], 0, 0, 0);
        acc[1][3] = __builtin_amdgcn_mfma_f32_16x16x32_bf16(a1, b3, acc[1][3], 0, 0, 0);
    }

    // direct epilogue: group-major store, bf16(h) partner from At
#pragma unroll
    for (int mt = 0; mt < 2; ++mt)
#pragma unroll
        for (int nt = 0; nt < 4; ++nt) {
            int col = n0 + nt * 16 + lm;
            int g = col >> 5, c = col & 31;
#pragma unroll
            for (int r = 0; r < 4; ++r) {
                int row = mt * 16 + (l >> 4) * 4 + r;
                unsigned u = (unsigned)bf16r(__expf(acc[mt][nt][r])) |
                             ((unsigned)At[row][col] << 16);
                packed[((size_t)g * N_NODES + (m0 + row)) * GCH + c] = u;
            }
        }
}

// ---------- merged independent work: gemm (blocks 0..624) | bucket scatter ----------
__global__ __launch_bounds__(256) void scatter_gemm_kernel(
        const float* __restrict__ h, const unsigned short* __restrict__ Wb,
        unsigned int* __restrict__ packed, const int* __restrict__ src,
        const int* __restrict__ dst, int* __restrict__ cnt,
        unsigned short* __restrict__ csr_src) {
    if (blockIdx.x < GEMM_BLOCKS) {
        __shared__ unsigned short At[32][LDS_PITCH];
        gemm_tile(h, Wb, packed, At, blockIdx.x, threadIdx.x);
    } else {
        int i = (blockIdx.x - GEMM_BLOCKS) * 256 + threadIdx.x;
        if (i < N_EDGES) {
            int d = dst[i];
            int slot = atomicAdd(&cnt[d], 1);
            slot = min(slot, CAP - 1);  // never OOB even on hypothetical overflow
            csr_src[(size_t)d * CAP + slot] = (unsigned short)src[i];
        }
    }
}

// ---------- aggregate: XCD-pinned groups, channel-local accumulation ----------
// Block bid: group g = bid&7 (== XCD under round-robin dispatch), 32 nodes.
// Lane = node_slot(l>>3) x ch_quad(l&7): each lane owns 4 channels of one node
// for the whole loop -> NO shuffles, NO butterfly, full-lane stores.  Per step
// the wave processes edge e of its 8 nodes (8 x 32 = 256 ch), loop bound is
// max degree over the 8 nodes (cndmask'd row-0 loads past a node's d).
#define PROC(p)                                                                  \
    {                                                                            \
        unsigned u;                                                              \
        float e, hv;                                                             \
        u = (p).x; e = __uint_as_float(u << 16);                                 \
        hv = __uint_as_float(u & 0xffff0000u); ss0 += e; a0 = fmaf(e, hv, a0);   \
        u = (p).y; e = __uint_as_float(u << 16);                                 \
        hv = __uint_as_float(u & 0xffff0000u); ss1 += e; a1 = fmaf(e, hv, a1);   \
        u = (p).z; e = __uint_as_float(u << 16);                                 \
        hv = __uint_as_float(u & 0xffff0000u); ss2 += e; a2 = fmaf(e, hv, a2);   \
        u = (p).w; e = __uint_as_float(u << 16);                                 \
        hv = __uint_as_float(u & 0xffff0000u); ss3 += e; a3 = fmaf(e, hv, a3);   \
    }
// safe predicated load: seg[e] is always in-bounds (CAP slots); select row 0
// when e >= d so the gather address is always valid, PROC skipped separately.
#define ELOAD(k) uint4 q##k; { int s = (int)seg[e + k];                          \
        s = (e + k < d) ? s : 0; q##k = pg[(size_t)s * 8 + c8]; }
#define EPROC(k) if (e + k < d) PROC(q##k)

__global__ __launch_bounds__(256) void aggregate_kernel(
        const float* __restrict__ h, const uint4* __restrict__ packed,
        const int* __restrict__ cnt, const unsigned short* __restrict__ csr_src,
        float* __restrict__ out) {
    int w = threadIdx.x >> 6, l = threadIdx.x & 63;
    int g = blockIdx.x & 7;               // == XCD under round-robin dispatch
    int node = (blockIdx.x >> 3) * 32 + w * 8 + (l >> 3);
    int c8 = l & 7;                       // ch quad within group
    int d = min(cnt[node], CAP);
    const unsigned short* seg = csr_src + (size_t)node * CAP;
    const uint4* pg = packed + (size_t)g * N_NODES * 8;  // 8 uint4 per node-row

    // wave-max degree (d constant across c8; xor over node-slot bits)
    int dmax = d;
#pragma unroll
    for (int st = 8; st < 64; st <<= 1) dmax = max(dmax, __shfl_xor(dmax, st));

    float ss0 = 0.f, ss1 = 0.f, ss2 = 0.f, ss3 = 0.f;
    float a0 = 0.f, a1 = 0.f, a2 = 0.f, a3 = 0.f;
    for (int e = 0; e < dmax; e += 4) {   // 4-deep load ILP
        ELOAD(0) ELOAD(1) ELOAD(2) ELOAD(3)
        EPROC(0); EPROC(1); EPROC(2); EPROC(3);
    }

    float4 o;
    if (d == 0) {  // zero in-degree: pass through h
        o = *(const float4*)(h + (size_t)node * EMB + g * GCH + c8 * 4);
    } else {
        o.x = a0 / ss0; o.y = a1 / ss1; o.z = a2 / ss2; o.w = a3 / ss3;
    }
    *(float4*)(out + (size_t)node * EMB + g * GCH + c8 * 4) = o;
}

// ---------- launch ----------
extern "C" void kernel_launch(void* const* d_in, const int* in_sizes, int n_in,
                              void* d_out, int out_size, void* d_ws, size_t ws_size,
                              hipStream_t stream) {
    const float* h      = (const float*)d_in[0];
    // W_nb (d_in[1]), b_nb (d_in[2]), b_self (d_in[4]) are mathematically
    // irrelevant: constant per (dst, channel) inside each softmax segment,
    // cancel exactly in alpha = e / seg_sum.
    const float* W_self = (const float*)d_in[3];
    const int*   src    = (const int*)d_in[5];
    const int*   dst    = (const int*)d_in[6];
    float* out = (float*)d_out;

    char* ws = (char*)d_ws;
    unsigned int* packed = (unsigned int*)ws;   // [8][N,32] group-major (E,h) pairs
    size_t off = (size_t)N_NODES * EMB * sizeof(unsigned int);
    unsigned short* Wb = (unsigned short*)(ws + off); off += (size_t)EMB * EMB * sizeof(unsigned short);
    int* cnt = (int*)(ws + off); off += (size_t)N_NODES * sizeof(int);
    unsigned short* csr_src = (unsigned short*)(ws + off);
    off += (size_t)N_NODES * CAP * sizeof(unsigned short);

    init_kernel<<<(N_NODES + 255) / 256, 256, 0, stream>>>(W_self, Wb, cnt);
    scatter_gemm_kernel<<<GEMM_BLOCKS + SCAT_BLOCKS, 256, 0, stream>>>(
        h, Wb, packed, src, dst, cnt, csr_src);
    aggregate_kernel<<<(N_NODES / 32) * NGRP, 256, 0, stream>>>(
        h, (const uint4*)packed, cnt, csr_src, out);
}

// Round 11
// 141.409 us; speedup vs baseline: 1.1205x; 1.0222x over previous
//
#include <hip/hip_runtime.h>
#include <math.h>

#define N_NODES 20000
#define N_EDGES 320000
#define EMB 256
#define CAP 64                              // slots per node; actual max in-degree ~34 (Poisson 16)
#define CNTS 32                             // cnt stride in ints: 1 counter per 128B L2 line
#define NGRP 8                              // channel groups == XCD count
#define GCH 32                              // channels per group
#define GEMM_BLOCKS (N_NODES / 32)          // 625
#define SCAT_BLOCKS ((N_EDGES + 255) / 256) // 1250
#define LDS_PITCH 264                       // 256 + 8 shorts: breaks bank-stride, keeps 16B align

typedef __attribute__((ext_vector_type(8))) short short8;
typedef __attribute__((ext_vector_type(4))) float floatx4;

__device__ __forceinline__ unsigned short bf16r(float x) {
    unsigned u = __float_as_uint(x);
    u += 0x7fffu + ((u >> 16) & 1u);
    return (unsigned short)(u >> 16);
}

// ---------- init: convert W_self to bf16 + zero padded slot counters ----------
__global__ __launch_bounds__(256) void init_kernel(
        const float* __restrict__ W, unsigned short* __restrict__ Wb,
        int* __restrict__ cnt) {
    int gid = blockIdx.x * 256 + threadIdx.x;
    if (gid < N_NODES) {
        // zero this node's 128B counter line (only word 0 is ever read)
        uint4 z = {0u, 0u, 0u, 0u};
        uint4* p = (uint4*)(cnt + ((size_t)gid << 5));
#pragma unroll
        for (int k = 0; k < 8; ++k) p[k] = z;
    }
    if (gid < (EMB * EMB) / 8) {
        long off = (long)gid * 8;
        float4 x = *(const float4*)(W + off);
        float4 y = *(const float4*)(W + off + 4);
        uint4 o;
        o.x = (unsigned)bf16r(x.x) | ((unsigned)bf16r(x.y) << 16);
        o.y = (unsigned)bf16r(x.z) | ((unsigned)bf16r(x.w) << 16);
        o.z = (unsigned)bf16r(y.x) | ((unsigned)bf16r(y.y) << 16);
        o.w = (unsigned)bf16r(y.z) | ((unsigned)bf16r(y.w) << 16);
        *(uint4*)(Wb + off) = o;
    }
}

// ---------------------------------------------------------------------------
// GEMM tile body: S = h @ W_self^T for 32 rows.  Output layout GROUP-MAJOR:
// packed[g][node][c] (g = ch>>5, c = ch&31): each group's gather slice is
// 2.56 MB — one XCD's L2 (FETCH 133->21 MB harness-verified R7).
// C/D layout (col=lane&15, row=(lane>>4)*4+reg) harness-verified R2..R9.
// ---------------------------------------------------------------------------
__device__ __forceinline__ void gemm_tile(
        const float* __restrict__ h, const unsigned short* __restrict__ Wb,
        unsigned int* __restrict__ packed, unsigned short (*At)[LDS_PITCH],
        int b, int t) {
    int w = t >> 6, l = t & 63;
    int m0 = b * 32;
    int n0 = w * 64;
    int lm = l & 15, lk = (l >> 4) * 8;

    // stage A: 32 rows x 256 cols fp32 -> bf16 LDS, coalesced float4 reads
#pragma unroll
    for (int it = 0; it < 8; ++it) {
        int q = it * 256 + t;            // [0, 2048)
        int row = q >> 6;                // 64 float4 per row
        int c4 = (q & 63) * 4;
        float4 x = *(const float4*)(h + (size_t)(m0 + row) * EMB + c4);
        At[row][c4 + 0] = bf16r(x.x);
        At[row][c4 + 1] = bf16r(x.y);
        At[row][c4 + 2] = bf16r(x.z);
        At[row][c4 + 3] = bf16r(x.w);
    }
    __syncthreads();

    floatx4 acc[2][4];
#pragma unroll
    for (int mt = 0; mt < 2; ++mt)
#pragma unroll
        for (int nt = 0; nt < 4; ++nt) acc[mt][nt] = (floatx4){0.f, 0.f, 0.f, 0.f};

    const unsigned short* a0p = &At[lm][lk];
    const unsigned short* a1p = &At[16 + lm][lk];
    const unsigned short* bp = Wb + (size_t)(n0 + lm) * EMB + lk;

#pragma unroll
    for (int k0 = 0; k0 < EMB; k0 += 32) {
        short8 a0 = *(const short8*)(a0p + k0);
        short8 a1 = *(const short8*)(a1p + k0);
        short8 b0 = *(const short8*)(bp + k0);
        short8 b1 = *(const short8*)(bp + 16 * EMB + k0);
        short8 b2 = *(const short8*)(bp + 32 * EMB + k0);
        short8 b3 = *(const short8*)(bp + 48 * EMB + k0);
        acc[0][0] = __builtin_amdgcn_mfma_f32_16x16x32_bf16(a0, b0, acc[0][0], 0, 0, 0);
        acc[0][1] = __builtin_amdgcn_mfma_f32_16x16x32_bf16(a0, b1, acc[0][1], 0, 0, 0);
        acc[0][2] = __builtin_amdgcn_mfma_f32_16x16x32_bf16(a0, b2, acc[0][2], 0, 0, 0);
        acc[0][3] = __builtin_amdgcn_mfma_f32_16x16x32_bf16(a0, b3, acc[0][3], 0, 0, 0);
        acc[1][0] = __builtin_amdgcn_mfma_f32_16x16x32_bf16(a1, b0, acc[1][0], 0, 0, 0);
        acc[1][1] = __builtin_amdgcn_mfma_f32_16x16x32_bf16(a1, b1, acc[1][1], 0, 0, 0);
        acc[1][2] = __builtin_amdgcn_mfma_f32_16x16x32_bf16(a1, b2, acc[1][2], 0, 0, 0);
        acc[1][3] = __builtin_amdgcn_mfma_f32_16x16x32_bf16(a1, b3, acc[1][3], 0, 0, 0);
    }

    // direct epilogue: group-major store, bf16(h) partner from At
#pragma unroll
    for (int mt = 0; mt < 2; ++mt)
#pragma unroll
        for (int nt = 0; nt < 4; ++nt) {
            int col = n0 + nt * 16 + lm;
            int g = col >> 5, c = col & 31;
#pragma unroll
            for (int r = 0; r < 4; ++r) {
                int row = mt * 16 + (l >> 4) * 4 + r;
                unsigned u = (unsigned)bf16r(__expf(acc[mt][nt][r])) |
                             ((unsigned)At[row][col] << 16);
                packed[((size_t)g * N_NODES + (m0 + row)) * GCH + c] = u;
            }
        }
}

// ---------- merged independent work: gemm (blocks 0..624) | bucket scatter ----------
// cnt padded 1 counter / 128B line: 320K atomics hit 20000 distinct lines
// instead of 625 (512-deep line serialization -> none).
__global__ __launch_bounds__(256) void scatter_gemm_kernel(
        const float* __restrict__ h, const unsigned short* __restrict__ Wb,
        unsigned int* __restrict__ packed, const int* __restrict__ src,
        const int* __restrict__ dst, int* __restrict__ cnt,
        unsigned short* __restrict__ csr_src) {
    if (blockIdx.x < GEMM_BLOCKS) {
        __shared__ unsigned short At[32][LDS_PITCH];
        gemm_tile(h, Wb, packed, At, blockIdx.x, threadIdx.x);
    } else {
        int i = (blockIdx.x - GEMM_BLOCKS) * 256 + threadIdx.x;
        if (i < N_EDGES) {
            int d = dst[i];
            int slot = atomicAdd(&cnt[(size_t)d << 5], 1);
            slot = min(slot, CAP - 1);  // never OOB even on hypothetical overflow
            csr_src[(size_t)d * CAP + slot] = (unsigned short)src[i];
        }
    }
}

// ---------- aggregate: XCD-pinned groups, channel-local accumulation ----------
// Block bid: group g = bid&7 (== XCD under round-robin dispatch), 32 nodes.
// Lane = node_slot(l>>3) x ch_quad(l&7): each lane owns 4 channels of one node
// for the whole loop -> NO shuffles, NO butterfly, full-lane stores.
#define PROC(p)                                                                  \
    {                                                                            \
        unsigned u;                                                              \
        float e, hv;                                                             \
        u = (p).x; e = __uint_as_float(u << 16);                                 \
        hv = __uint_as_float(u & 0xffff0000u); ss0 += e; a0 = fmaf(e, hv, a0);   \
        u = (p).y; e = __uint_as_float(u << 16);                                 \
        hv = __uint_as_float(u & 0xffff0000u); ss1 += e; a1 = fmaf(e, hv, a1);   \
        u = (p).z; e = __uint_as_float(u << 16);                                 \
        hv = __uint_as_float(u & 0xffff0000u); ss2 += e; a2 = fmaf(e, hv, a2);   \
        u = (p).w; e = __uint_as_float(u << 16);                                 \
        hv = __uint_as_float(u & 0xffff0000u); ss3 += e; a3 = fmaf(e, hv, a3);   \
    }
// safe predicated load: seg[e] always in-bounds (CAP slots); row 0 past d.
#define ELOAD(k) uint4 q##k; { int s = (int)seg[e + k];                          \
        s = (e + k < d) ? s : 0; q##k = pg[(size_t)s * 8 + c8]; }
#define EPROC(k) if (e + k < d) PROC(q##k)

__global__ __launch_bounds__(256) void aggregate_kernel(
        const float* __restrict__ h, const uint4* __restrict__ packed,
        const int* __restrict__ cnt, const unsigned short* __restrict__ csr_src,
        float* __restrict__ out) {
    int w = threadIdx.x >> 6, l = threadIdx.x & 63;
    int g = blockIdx.x & 7;               // == XCD under round-robin dispatch
    int node = (blockIdx.x >> 3) * 32 + w * 8 + (l >> 3);
    int c8 = l & 7;                       // ch quad within group
    int d = min(cnt[(size_t)node << 5], CAP);
    const unsigned short* seg = csr_src + (size_t)node * CAP;
    const uint4* pg = packed + (size_t)g * N_NODES * 8;  // 8 uint4 per node-row

    // wave-max degree (d constant across c8; xor over node-slot bits)
    int dmax = d;
#pragma unroll
    for (int st = 8; st < 64; st <<= 1) dmax = max(dmax, __shfl_xor(dmax, st));

    float ss0 = 0.f, ss1 = 0.f, ss2 = 0.f, ss3 = 0.f;
    float a0 = 0.f, a1 = 0.f, a2 = 0.f, a3 = 0.f;
    for (int e = 0; e < dmax; e += 4) {   // 4-deep load ILP
        ELOAD(0) ELOAD(1) ELOAD(2) ELOAD(3)
        EPROC(0); EPROC(1); EPROC(2); EPROC(3);
    }

    floatx4 o;
    if (d == 0) {  // zero in-degree: pass through h
        const float* hp = h + (size_t)node * EMB + g * GCH + c8 * 4;
        o = *(const floatx4*)hp;
    } else {
        o[0] = a0 / ss0; o[1] = a1 / ss1; o[2] = a2 / ss2; o[3] = a3 / ss3;
    }
    // out is written once and never read on-device: non-temporal keeps the
    // XCD's L2 free for the pinned packed slice.  (native vector type: the
    // builtin rejects HIP_vector_type float4 — R10 compile error.)
    __builtin_nontemporal_store(o, (floatx4*)(out + (size_t)node * EMB + g * GCH + c8 * 4));
}

// ---------- launch ----------
extern "C" void kernel_launch(void* const* d_in, const int* in_sizes, int n_in,
                              void* d_out, int out_size, void* d_ws, size_t ws_size,
                              hipStream_t stream) {
    const float* h      = (const float*)d_in[0];
    // W_nb (d_in[1]), b_nb (d_in[2]), b_self (d_in[4]) are mathematically
    // irrelevant: constant per (dst, channel) inside each softmax segment,
    // cancel exactly in alpha = e / seg_sum.
    const float* W_self = (const float*)d_in[3];
    const int*   src    = (const int*)d_in[5];
    const int*   dst    = (const int*)d_in[6];
    float* out = (float*)d_out;

    char* ws = (char*)d_ws;
    unsigned int* packed = (unsigned int*)ws;   // [8][N,32] group-major (E,h) pairs
    size_t off = (size_t)N_NODES * EMB * sizeof(unsigned int);
    unsigned short* Wb = (unsigned short*)(ws + off); off += (size_t)EMB * EMB * sizeof(unsigned short);
    int* cnt = (int*)(ws + off); off += (size_t)N_NODES * CNTS * sizeof(int);
    unsigned short* csr_src = (unsigned short*)(ws + off);
    off += (size_t)N_NODES * CAP * sizeof(unsigned short);

    init_kernel<<<(N_NODES + 255) / 256, 256, 0, stream>>>(W_self, Wb, cnt);
    scatter_gemm_kernel<<<GEMM_BLOCKS + SCAT_BLOCKS, 256, 0, stream>>>(
        h, Wb, packed, src, dst, cnt, csr_src);
    aggregate_kernel<<<(N_NODES / 32) * NGRP, 256, 0, stream>>>(
        h, (const uint4*)packed, cnt, csr_src, out);
}

// Round 12
// 131.299 us; speedup vs baseline: 1.2067x; 1.0770x over previous
//
#include <hip/hip_runtime.h>
#include <math.h>

#define N_NODES 20000
#define N_EDGES 320000
#define EMB 256
#define CAP 64                              // slots per node; actual max in-degree ~34 (Poisson 16)
#define CNTS 32                             // cnt stride in ints: 1 counter per 128B L2 line
#define NGRP 8                              // channel groups == XCD count
#define GCH 32                              // channels per group
#define GEMM_BLOCKS (N_NODES / 32)          // 625
#define SCAT_BLOCKS ((N_EDGES + 255) / 256) // 1250
#define LDS_PITCH 264                       // 256 + 8 shorts: breaks bank-stride, keeps 16B align

typedef __attribute__((ext_vector_type(8))) short short8;
typedef __attribute__((ext_vector_type(4))) float floatx4;

__device__ __forceinline__ unsigned short bf16r(float x) {
    unsigned u = __float_as_uint(x);
    u += 0x7fffu + ((u >> 16) & 1u);
    return (unsigned short)(u >> 16);
}

// ---------- init: convert W_self to bf16 + zero padded slot counters ----------
__global__ __launch_bounds__(256) void init_kernel(
        const float* __restrict__ W, unsigned short* __restrict__ Wb,
        int* __restrict__ cnt) {
    int gid = blockIdx.x * 256 + threadIdx.x;
    if (gid < N_NODES) {
        // zero this node's 128B counter line (only word 0 is ever read)
        uint4 z = {0u, 0u, 0u, 0u};
        uint4* p = (uint4*)(cnt + ((size_t)gid << 5));
#pragma unroll
        for (int k = 0; k < 8; ++k) p[k] = z;
    }
    if (gid < (EMB * EMB) / 8) {
        long off = (long)gid * 8;
        float4 x = *(const float4*)(W + off);
        float4 y = *(const float4*)(W + off + 4);
        uint4 o;
        o.x = (unsigned)bf16r(x.x) | ((unsigned)bf16r(x.y) << 16);
        o.y = (unsigned)bf16r(x.z) | ((unsigned)bf16r(x.w) << 16);
        o.z = (unsigned)bf16r(y.x) | ((unsigned)bf16r(y.y) << 16);
        o.w = (unsigned)bf16r(y.z) | ((unsigned)bf16r(y.w) << 16);
        *(uint4*)(Wb + off) = o;
    }
}

// ---------------------------------------------------------------------------
// GEMM tile body: S = h @ W_self^T for 32 rows.  Output layout GROUP-MAJOR:
// packed[g][node][c] (g = ch>>5, c = ch&31): each group's gather slice is
// 2.56 MB — one XCD's L2 (FETCH 133->21 MB harness-verified R7).
// C/D layout (col=lane&15, row=(lane>>4)*4+reg) harness-verified R2..R11.
// ---------------------------------------------------------------------------
__device__ __forceinline__ void gemm_tile(
        const float* __restrict__ h, const unsigned short* __restrict__ Wb,
        unsigned int* __restrict__ packed, unsigned short (*At)[LDS_PITCH],
        int b, int t) {
    int w = t >> 6, l = t & 63;
    int m0 = b * 32;
    int n0 = w * 64;
    int lm = l & 15, lk = (l >> 4) * 8;

    // stage A: 32 rows x 256 cols fp32 -> bf16 LDS, coalesced float4 reads
#pragma unroll
    for (int it = 0; it < 8; ++it) {
        int q = it * 256 + t;            // [0, 2048)
        int row = q >> 6;                // 64 float4 per row
        int c4 = (q & 63) * 4;
        float4 x = *(const float4*)(h + (size_t)(m0 + row) * EMB + c4);
        At[row][c4 + 0] = bf16r(x.x);
        At[row][c4 + 1] = bf16r(x.y);
        At[row][c4 + 2] = bf16r(x.z);
        At[row][c4 + 3] = bf16r(x.w);
    }
    __syncthreads();

    floatx4 acc[2][4];
#pragma unroll
    for (int mt = 0; mt < 2; ++mt)
#pragma unroll
        for (int nt = 0; nt < 4; ++nt) acc[mt][nt] = (floatx4){0.f, 0.f, 0.f, 0.f};

    const unsigned short* a0p = &At[lm][lk];
    const unsigned short* a1p = &At[16 + lm][lk];
    const unsigned short* bp = Wb + (size_t)(n0 + lm) * EMB + lk;

#pragma unroll
    for (int k0 = 0; k0 < EMB; k0 += 32) {
        short8 a0 = *(const short8*)(a0p + k0);
        short8 a1 = *(const short8*)(a1p + k0);
        short8 b0 = *(const short8*)(bp + k0);
        short8 b1 = *(const short8*)(bp + 16 * EMB + k0);
        short8 b2 = *(const short8*)(bp + 32 * EMB + k0);
        short8 b3 = *(const short8*)(bp + 48 * EMB + k0);
        acc[0][0] = __builtin_amdgcn_mfma_f32_16x16x32_bf16(a0, b0, acc[0][0], 0, 0, 0);
        acc[0][1] = __builtin_amdgcn_mfma_f32_16x16x32_bf16(a0, b1, acc[0][1], 0, 0, 0);
        acc[0][2] = __builtin_amdgcn_mfma_f32_16x16x32_bf16(a0, b2, acc[0][2], 0, 0, 0);
        acc[0][3] = __builtin_amdgcn_mfma_f32_16x16x32_bf16(a0, b3, acc[0][3], 0, 0, 0);
        acc[1][0] = __builtin_amdgcn_mfma_f32_16x16x32_bf16(a1, b0, acc[1][0], 0, 0, 0);
        acc[1][1] = __builtin_amdgcn_mfma_f32_16x16x32_bf16(a1, b1, acc[1][1], 0, 0, 0);
        acc[1][2] = __builtin_amdgcn_mfma_f32_16x16x32_bf16(a1, b2, acc[1][2], 0, 0, 0);
        acc[1][3] = __builtin_amdgcn_mfma_f32_16x16x32_bf16(a1, b3, acc[1][3], 0, 0, 0);
    }

    // direct epilogue: group-major store, bf16(h) partner from At
#pragma unroll
    for (int mt = 0; mt < 2; ++mt)
#pragma unroll
        for (int nt = 0; nt < 4; ++nt) {
            int col = n0 + nt * 16 + lm;
            int g = col >> 5, c = col & 31;
#pragma unroll
            for (int r = 0; r < 4; ++r) {
                int row = mt * 16 + (l >> 4) * 4 + r;
                unsigned u = (unsigned)bf16r(__expf(acc[mt][nt][r])) |
                             ((unsigned)At[row][col] << 16);
                packed[((size_t)g * N_NODES + (m0 + row)) * GCH + c] = u;
            }
        }
}

// ---------- merged independent work: gemm (blocks 0..624) | bucket scatter ----------
__global__ __launch_bounds__(256) void scatter_gemm_kernel(
        const float* __restrict__ h, const unsigned short* __restrict__ Wb,
        unsigned int* __restrict__ packed, const int* __restrict__ src,
        const int* __restrict__ dst, int* __restrict__ cnt,
        unsigned short* __restrict__ csr_src) {
    if (blockIdx.x < GEMM_BLOCKS) {
        __shared__ unsigned short At[32][LDS_PITCH];
        gemm_tile(h, Wb, packed, At, blockIdx.x, threadIdx.x);
    } else {
        int i = (blockIdx.x - GEMM_BLOCKS) * 256 + threadIdx.x;
        if (i < N_EDGES) {
            int d = dst[i];
            int slot = atomicAdd(&cnt[(size_t)d << 5], 1);
            slot = min(slot, CAP - 1);  // never OOB even on hypothetical overflow
            csr_src[(size_t)d * CAP + slot] = (unsigned short)src[i];
        }
    }
}

// ---------- aggregate: XCD-pinned groups, reg-resident slot list ----------
// The node's slot list (slots 0..31, 64B) is preloaded into 4 uint4 regs; slot
// extraction is 2 VALU bit-ops with COMPILE-TIME register indices (4 chunks x 8
// unrolled) — removes the per-edge seg VMEM load from the gather address chain
// and deepens gather ILP to 8.  d>32 (P~1e-4/node) falls to the memory tail.
#define PROC(p)                                                                  \
    {                                                                            \
        unsigned u;                                                              \
        float e, hv;                                                             \
        u = (p).x; e = __uint_as_float(u << 16);                                 \
        hv = __uint_as_float(u & 0xffff0000u); ss0 += e; a0 = fmaf(e, hv, a0);   \
        u = (p).y; e = __uint_as_float(u << 16);                                 \
        hv = __uint_as_float(u & 0xffff0000u); ss1 += e; a1 = fmaf(e, hv, a1);   \
        u = (p).z; e = __uint_as_float(u << 16);                                 \
        hv = __uint_as_float(u & 0xffff0000u); ss2 += e; a2 = fmaf(e, hv, a2);   \
        u = (p).w; e = __uint_as_float(u << 16);                                 \
        hv = __uint_as_float(u & 0xffff0000u); ss3 += e; a3 = fmaf(e, hv, a3);   \
    }
// memory-tail load (e >= 32 only): safe row-0 address past d
#define ELOAD(k) uint4 q##k; { int s = (int)seg[e + k];                          \
        s = (e + k < d) ? s : 0; q##k = pg[(size_t)s * 8 + c8]; }
#define EPROC(k) if (e + k < d) PROC(q##k)
// chunk C: slots 8C..8C+7 extracted from preloaded uint4 sc (little-endian)
#define GCHUNK(C, sc)                                                            \
    if ((C) * 8 < dmax) {                                                        \
        int t0 = (int)((sc).x & 0xffffu), t1 = (int)((sc).x >> 16);              \
        int t2 = (int)((sc).y & 0xffffu), t3 = (int)((sc).y >> 16);              \
        int t4 = (int)((sc).z & 0xffffu), t5 = (int)((sc).z >> 16);              \
        int t6 = (int)((sc).w & 0xffffu), t7 = (int)((sc).w >> 16);              \
        uint4 q0 = pg[(size_t)((C)*8 + 0 < d ? t0 : 0) * 8 + c8];                \
        uint4 q1 = pg[(size_t)((C)*8 + 1 < d ? t1 : 0) * 8 + c8];                \
        uint4 q2 = pg[(size_t)((C)*8 + 2 < d ? t2 : 0) * 8 + c8];                \
        uint4 q3 = pg[(size_t)((C)*8 + 3 < d ? t3 : 0) * 8 + c8];                \
        uint4 q4 = pg[(size_t)((C)*8 + 4 < d ? t4 : 0) * 8 + c8];                \
        uint4 q5 = pg[(size_t)((C)*8 + 5 < d ? t5 : 0) * 8 + c8];                \
        uint4 q6 = pg[(size_t)((C)*8 + 6 < d ? t6 : 0) * 8 + c8];                \
        uint4 q7 = pg[(size_t)((C)*8 + 7 < d ? t7 : 0) * 8 + c8];                \
        if ((C)*8 + 0 < d) PROC(q0); if ((C)*8 + 1 < d) PROC(q1);                \
        if ((C)*8 + 2 < d) PROC(q2); if ((C)*8 + 3 < d) PROC(q3);                \
        if ((C)*8 + 4 < d) PROC(q4); if ((C)*8 + 5 < d) PROC(q5);                \
        if ((C)*8 + 6 < d) PROC(q6); if ((C)*8 + 7 < d) PROC(q7);                \
    }

__global__ __launch_bounds__(256) void aggregate_kernel(
        const float* __restrict__ h, const uint4* __restrict__ packed,
        const int* __restrict__ cnt, const unsigned short* __restrict__ csr_src,
        float* __restrict__ out) {
    int w = threadIdx.x >> 6, l = threadIdx.x & 63;
    int g = blockIdx.x & 7;               // == XCD under round-robin dispatch
    int node = (blockIdx.x >> 3) * 32 + w * 8 + (l >> 3);
    int c8 = l & 7;                       // ch quad within group
    int d = min(cnt[(size_t)node << 5], CAP);
    const unsigned short* seg = csr_src + (size_t)node * CAP;
    const uint4* seg4 = (const uint4*)seg;               // 128B-aligned
    const uint4* pg = packed + (size_t)g * N_NODES * 8;  // 8 uint4 per node-row

    // wave-max degree (d constant across c8; xor over node-slot bits)
    int dmax = d;
#pragma unroll
    for (int st = 8; st < 64; st <<= 1) dmax = max(dmax, __shfl_xor(dmax, st));

    // preload slots 0..31 (covers d<=32; P(d>32) ~1e-4): 4 independent loads
    uint4 sA = seg4[0], sB = seg4[1], sC = seg4[2], sD = seg4[3];

    float ss0 = 0.f, ss1 = 0.f, ss2 = 0.f, ss3 = 0.f;
    float a0 = 0.f, a1 = 0.f, a2 = 0.f, a3 = 0.f;
    GCHUNK(0, sA)
    GCHUNK(1, sB)
    GCHUNK(2, sC)
    GCHUNK(3, sD)
    if (dmax > 32) {                      // rare memory tail
        for (int e = 32; e < dmax; e += 4) {
            ELOAD(0) ELOAD(1) ELOAD(2) ELOAD(3)
            EPROC(0); EPROC(1); EPROC(2); EPROC(3);
        }
    }

    floatx4 o;
    if (d == 0) {  // zero in-degree: pass through h
        const float* hp = h + (size_t)node * EMB + g * GCH + c8 * 4;
        o = *(const floatx4*)hp;
    } else {
        o[0] = a0 / ss0; o[1] = a1 / ss1; o[2] = a2 / ss2; o[3] = a3 / ss3;
    }
    // out written once, never read on-device: non-temporal keeps L2 clean
    __builtin_nontemporal_store(o, (floatx4*)(out + (size_t)node * EMB + g * GCH + c8 * 4));
}

// ---------- launch ----------
extern "C" void kernel_launch(void* const* d_in, const int* in_sizes, int n_in,
                              void* d_out, int out_size, void* d_ws, size_t ws_size,
                              hipStream_t stream) {
    const float* h      = (const float*)d_in[0];
    // W_nb (d_in[1]), b_nb (d_in[2]), b_self (d_in[4]) are mathematically
    // irrelevant: constant per (dst, channel) inside each softmax segment,
    // cancel exactly in alpha = e / seg_sum.
    const float* W_self = (const float*)d_in[3];
    const int*   src    = (const int*)d_in[5];
    const int*   dst    = (const int*)d_in[6];
    float* out = (float*)d_out;

    char* ws = (char*)d_ws;
    unsigned int* packed = (unsigned int*)ws;   // [8][N,32] group-major (E,h) pairs
    size_t off = (size_t)N_NODES * EMB * sizeof(unsigned int);
    unsigned short* Wb = (unsigned short*)(ws + off); off += (size_t)EMB * EMB * sizeof(unsigned short);
    int* cnt = (int*)(ws + off); off += (size_t)N_NODES * CNTS * sizeof(int);
    unsigned short* csr_src = (unsigned short*)(ws + off);
    off += (size_t)N_NODES * CAP * sizeof(unsigned short);

    init_kernel<<<(N_NODES + 255) / 256, 256, 0, stream>>>(W_self, Wb, cnt);
    scatter_gemm_kernel<<<GEMM_BLOCKS + SCAT_BLOCKS, 256, 0, stream>>>(
        h, Wb, packed, src, dst, cnt, csr_src);
    aggregate_kernel<<<(N_NODES / 32) * NGRP, 256, 0, stream>>>(
        h, (const uint4*)packed, cnt, csr_src, out);
}